// Round 5
// baseline (208.391 us; speedup 1.0000x reference)
//
#include <hip/hip_runtime.h>
#include <hip/hip_bf16.h>

#define NN 50000
#define FIN 128
#define NT (NN / 16)   // 3125 row-tiles of 16
#define NREG 196       // ceil(NN/256) 256-node regions
#define SLAB 8960      // fixed per-region CSR slab (max padded region ~8150)
#define NBINB 512      // binA chunks (1562 edges each)
#define CAP2 32        // per-(chunk,region) cell capacity = one 128B line
#define NGEMB ((NT + 3) / 4)  // 782 GEMM blocks
#define STCAP 5200     // LDS stage capacity (region mean 4082, +17 sigma)
#define REPS 2         // INSTRUMENTATION: run each phase twice (idempotent)
                       // so every >22us phase clears the ~44us poison-fill
                       // band and surfaces in rocprof top-5 with counters.
                       // True per-phase cost = dur/REPS, counters/REPS.

typedef unsigned char u8;
typedef unsigned short u16;
typedef unsigned int u32;
typedef __attribute__((ext_vector_type(8))) short short8;
typedef __attribute__((ext_vector_type(4))) float floatx4;

__device__ __forceinline__ float b2f(u16 v) {
  union { u32 u; float f; } x; x.u = ((u32)v) << 16; return x.f;
}
__device__ __forceinline__ u16 f2b(float f) {
  union { u32 u; float f; } x; x.f = f;
  u32 r = x.u + 0x7FFFu + ((x.u >> 16) & 1u);  // round-nearest-even
  return (u16)(r >> 16);
}

// K0: three independent parts in one launch (no cross-block deps):
//  blk 0            : w2f = W2@Wfc, cbias, flags[0] (x fmt), sentinels.
//  blk 1..NBINB     : one-pass edge binning into fixed (chunk,region) cells.
//  blk NBINB+1..    : self-contained MFMA GEMM  gf = x @ W1  (f32, UNSCALED).
__global__ __launch_bounds__(256) void k_prep_bin_gemm(
    const u32* __restrict__ xw, int nxw, const void* __restrict__ w1, int n1w,
    const void* __restrict__ w2, int n2w, const void* __restrict__ wf, int nfw,
    const u16* __restrict__ b2, const u16* __restrict__ bfc,
    float* __restrict__ w2f, float* __restrict__ cbias, int* __restrict__ flags,
    const int* __restrict__ src, const int* __restrict__ dst, int E,
    u32* __restrict__ bucket, u8* __restrict__ cntm,
    const void* __restrict__ X, float* __restrict__ gf,
    u16* __restrict__ g, float* __restrict__ tvec) {
  int t = threadIdx.x;
  int blk = blockIdx.x;
  if (blk >= 1 && blk <= NBINB) {  // ---- one-pass binning ----
    __shared__ int cnt2[NREG];
    int sl = blk - 1;
    int lo = (int)((long long)sl * E / NBINB);
    int hi = (int)((long long)(sl + 1) * E / NBINB);
    for (int rep = 0; rep < REPS; ++rep) {
      for (int i = t; i < NREG; i += 256) cnt2[i] = 0;
      __syncthreads();
      for (int e = lo + t; e < hi; e += 256) {
        int d = dst[e];
        int s = src[e];
        int r = d >> 8;
        int ofs = atomicAdd(&cnt2[r], 1);
        if (ofs < CAP2)
          bucket[((size_t)sl * NREG + r) * CAP2 + ofs] =
              ((u32)(d & 255) << 16) | (u32)s;
      }
      __syncthreads();
      for (int i = t; i < NREG; i += 256) {
        int c = cnt2[i];
        cntm[(size_t)sl * NREG + i] = (u8)(c > CAP2 ? CAP2 : c);
      }
      __syncthreads();
    }
    return;
  }
  if (blk == 0) {  // ---- misc: flags, w2f, cbias, sentinels ----
    __shared__ int sc[3];
    for (int rep = 0; rep < REPS; ++rep) {
      if (t < 3) sc[t] = 0;
      __syncthreads();
      const u32* p2 = (const u32*)w2;
      const u32* pf = (const u32*)wf;
      int n2s = n2w < 1024 ? n2w : 1024;
      int nfs = nfw < 1024 ? nfw : 1024;
      int sn = nxw < 1024 ? nxw : 1024;
      int s2 = 0, sf = 0, sx = 0;
      for (int i = t; i < n2s; i += 256) {
        u32 w = p2[i];
        u32 e = (w >> 7) & 0xFFu;
        s2 += (e >= 100u && e <= 132u) ? 1 : -1;
      }
      for (int i = t; i < nfs; i += 256) {
        u32 w = pf[i];
        u32 e = (w >> 7) & 0xFFu;
        sf += (e >= 100u && e <= 132u) ? 1 : -1;
      }
      for (int i = t; i < sn; i += 256) {
        u32 w = xw[i];
        u32 e = (w >> 7) & 0xFFu;
        sx += (e >= 100u && e <= 132u) ? 1 : -1;
      }
      if (s2) atomicAdd(&sc[0], s2);
      if (sf) atomicAdd(&sc[1], sf);
      if (sx) atomicAdd(&sc[2], sx);
      __syncthreads();
      int f2 = sc[0] > 0, f3 = sc[1] > 0;
      if (t == 0) { flags[0] = sc[2] > 0; flags[2] = f2; flags[3] = f3; }
      if (t < 64) {
        float acc = 0.f;
        for (int j = 0; j < 64; ++j) {
          float w2v = f2 ? b2f(((const u16*)w2)[t * 64 + j])
                         : ((const float*)w2)[t * 64 + j];
          float wfv = f3 ? b2f(((const u16*)wf)[j]) : ((const float*)wf)[j];
          acc += w2v * wfv;
        }
        w2f[t] = acc;
      } else if (t == 64) {
        float acc = b2f(bfc[0]);
        for (int j = 0; j < 64; ++j) {
          float wfv = f3 ? b2f(((const u16*)wf)[j]) : ((const float*)wf)[j];
          acc += b2f(b2[j]) * wfv;
        }
        cbias[0] = acc;
      } else if (t >= 128 && t < 192) {
        g[(size_t)NN * 64 + (t - 128)] = 0;  // sentinel row g[NN] = 0
      } else if (t == 192) {
        tvec[NN] = 0.f;  // sentinel tscaled[NN] = 0
      }
      __syncthreads();
    }
    return;
  }
  // ---- GEMM: gf = x @ W1 (f32, unscaled) ----
  __shared__ u16 lwh[FIN * 64];
  __shared__ u16 lwl[FIN * 64];
  __shared__ int scg[2];
  if (t < 2) scg[t] = 0;
  __syncthreads();
  {  // self-detect x / W1 formats (deterministic, same result in every block)
    int sn = nxw < 1024 ? nxw : 1024;
    int sx = 0;
    for (int i = t; i < sn; i += 256) {
      u32 w = xw[i];
      u32 e = (w >> 7) & 0xFFu;
      sx += (e >= 100u && e <= 132u) ? 1 : -1;
    }
    if (sx) atomicAdd(&scg[0], sx);
    int s1n = n1w < 1024 ? n1w : 1024;
    const u32* p1 = (const u32*)w1;
    int s1 = 0;
    for (int i = t; i < s1n; i += 256) {
      u32 w = p1[i];
      u32 e = (w >> 7) & 0xFFu;
      s1 += (e >= 100u && e <= 132u) ? 1 : -1;
    }
    if (s1) atomicAdd(&scg[1], s1);
  }
  __syncthreads();
  bool xb = scg[0] > 0;
  bool w1b = scg[1] > 0;
  for (int i = t; i < FIN * 64; i += 256) {
    int j = i & 7, L = (i >> 3) & 63, f = i >> 9;
    int k = (f >> 2) * 32 + (L >> 4) * 8 + j;
    int n = (f & 3) * 16 + (L & 15);
    int idx = k * 64 + n;
    float v = w1b ? b2f(((const u16*)w1)[idx]) : ((const float*)w1)[idx];
    u16 hb = f2b(v);
    lwh[i] = hb;
    lwl[i] = f2b(v - b2f(hb));
  }
  __syncthreads();
  constexpr int KC = FIN / 32;
  int wave = t >> 6, lane = t & 63;
  int rt = (blk - NBINB - 1) * 4 + wave;
  for (int rep = 0; rep < REPS; ++rep) {
    if (rt < NT) {
      int m = rt * 16 + (lane & 15);
      int q = (lane >> 4) * 8;
      short8 ah[KC], al[KC];
      if (xb) {
        const u16* xr = (const u16*)X + (size_t)m * FIN + q;
#pragma unroll
        for (int kc = 0; kc < KC; ++kc) ah[kc] = *(const short8*)(xr + kc * 32);
      } else {
        const float* xr = (const float*)X + (size_t)m * FIN + q;
#pragma unroll
        for (int kc = 0; kc < KC; ++kc) {
          float4 v0 = *(const float4*)(xr + kc * 32);
          float4 v1 = *(const float4*)(xr + kc * 32 + 4);
          float v[8] = {v0.x, v0.y, v0.z, v0.w, v1.x, v1.y, v1.z, v1.w};
          short8 h8, l8;
#pragma unroll
          for (int j = 0; j < 8; ++j) {
            u16 hb = f2b(v[j]);
            h8[j] = (short)hb;
            l8[j] = (short)f2b(v[j] - b2f(hb));
          }
          ah[kc] = h8;
          al[kc] = l8;
        }
      }
      int row0 = rt * 16 + (lane >> 4) * 4;
      int c0 = lane & 15;
#pragma unroll
      for (int ct = 0; ct < 4; ++ct) {
        short8 bh[KC], bl[KC];
#pragma unroll
        for (int kc = 0; kc < KC; ++kc) {
          int fo = ((kc * 4 + ct) * 64 + lane) * 8;
          bh[kc] = *(const short8*)(lwh + fo);
          bl[kc] = *(const short8*)(lwl + fo);
        }
        floatx4 acc = (floatx4)(0.f);
#pragma unroll
        for (int kc = 0; kc < KC; ++kc) {
          if (!xb)
            acc = __builtin_amdgcn_mfma_f32_16x16x32_bf16(al[kc], bh[kc], acc, 0, 0, 0);
          acc = __builtin_amdgcn_mfma_f32_16x16x32_bf16(ah[kc], bl[kc], acc, 0, 0, 0);
          acc = __builtin_amdgcn_mfma_f32_16x16x32_bf16(ah[kc], bh[kc], acc, 0, 0, 0);
        }
        size_t o = (size_t)row0 * 64 + ct * 16 + c0;
#pragma unroll
        for (int r = 0; r < 4; ++r) gf[o + (size_t)r * 64] = acc[r];
      }
    }
  }
}

// K1: one block per region (512 thr). Scan 512 chunk counts -> gather cells
// into LDS stage -> node histogram -> rowstart/cnt -> csr scatter + sentinel
// pad -> dinv-scale gf (f32) into g (bf16) for this region's 256 rows.
__global__ __launch_bounds__(512) void k_assemble(
    const u32* __restrict__ bucket, const u8* __restrict__ cntm,
    int* __restrict__ rowstart, int* __restrict__ cnt, u16* __restrict__ csr,
    const float* __restrict__ gf, u16* __restrict__ g) {
  __shared__ u32 stage[STCAP];
  __shared__ int h[256];
  __shared__ int off[256];
  __shared__ int wsum[8];
  __shared__ int nws[4];
  __shared__ int tot_s;
  int r = blockIdx.x, t = threadIdx.x;
  int lane = t & 63, w = t >> 6;
  for (int rep = 0; rep < REPS; ++rep) {
    int c = (int)cntm[(size_t)t * NREG + r];
    int xv = c;
    for (int d = 1; d < 64; d <<= 1) {
      int y = __shfl_up(xv, d);
      if (lane >= d) xv += y;
    }
    if (lane == 63) wsum[w] = xv;
    if (t < 256) h[t] = 0;
    __syncthreads();
    int add = 0;
    for (int j = 0; j < w; ++j) add += wsum[j];
    int beg = xv + add - c;
    if (t == 0) {
      int tt = 0;
      for (int j = 0; j < 8; ++j) tt += wsum[j];
      tot_s = tt > STCAP ? STCAP : tt;
    }
    const u32* b = bucket + ((size_t)t * NREG + r) * CAP2;
    for (int i = 0; i < c; ++i) {
      int p = beg + i;
      if (p < STCAP) stage[p] = b[i];
    }
    __syncthreads();
    int tot = tot_s;
    for (int i = t; i < tot; i += 512) atomicAdd(&h[stage[i] >> 16], 1);
    __syncthreads();
    int grs = 0, p16 = 0, hc = 0, sv = 0;
    if (t < 256) {
      hc = h[t];
      p16 = (hc + 15) & ~15;
      sv = p16;
      for (int d = 1; d < 64; d <<= 1) {
        int y = __shfl_up(sv, d);
        if (lane >= d) sv += y;
      }
      if (lane == 63) nws[w] = sv;
    }
    __syncthreads();
    if (t < 256) {
      int a2 = 0;
      for (int j = 0; j < w; ++j) a2 += nws[j];
      sv += a2;
      grs = r * SLAB + sv - p16;
      int v = r * 256 + t;
      if (v < NN) { rowstart[v] = grs; cnt[v] = hc; }
      off[t] = grs;
    }
    __syncthreads();
    for (int i = t; i < tot; i += 512) {
      u32 pk = stage[i];
      int pos = atomicAdd(&off[pk >> 16], 1);
      csr[pos] = (u16)(pk & 0xFFFFu);
    }
    __syncthreads();
    if (t < 256) {
      int v = r * 256 + t;
      if (v < NN) {
        int end = grs + p16;
        for (int pos = off[t]; pos < end; ++pos) csr[pos] = (u16)NN;
      }
    }
    {
      int row = r * 256 + (t >> 1);
      int half = t & 1;
      if (row < NN) {
        float dv = rsqrtf((float)(h[t >> 1] + 1));
        const float* gr = gf + (size_t)row * 64 + half * 32;
        u16* go = g + (size_t)row * 64 + half * 32;
#pragma unroll
        for (int k2 = 0; k2 < 4; ++k2) {
          float4 a = *(const float4*)(gr + k2 * 8);
          float4 b4 = *(const float4*)(gr + k2 * 8 + 4);
          float v[8] = {a.x, a.y, a.z, a.w, b4.x, b4.y, b4.z, b4.w};
          short8 o8;
#pragma unroll
          for (int j = 0; j < 8; ++j) o8[j] = (short)f2b(v[j] * dv);
          *(short8*)(go + k2 * 8) = o8;
        }
      }
    }
    __syncthreads();  // protect LDS before next rep re-inits
  }
}

// K2: layer-1 agg + relu + head projection, FOUR nodes/wave.
__global__ __launch_bounds__(256) void k_agg1t(const u16* __restrict__ g,
                                               const int* __restrict__ cnt,
                                               const int* __restrict__ rowstart,
                                               const u16* __restrict__ csr,
                                               const u16* __restrict__ bias,
                                               const float* __restrict__ w2f,
                                               float* __restrict__ tvec) {
  int tid = threadIdx.x;
  int wave = tid >> 6, lane = tid & 63;
  int v = (blockIdx.x * 4 + wave) * 4;  // NN%16==0 -> v+3 < NN
  for (int rep = 0; rep < REPS; ++rep) {
    int rs[4], pd[4];
    float dvl[4], acc[4];
    int pm = 0;
#pragma unroll
    for (int n = 0; n < 4; ++n) {
      rs[n] = rowstart[v + n];
      int c = cnt[v + n];
      pd[n] = (c + 15) & ~15;
      dvl[n] = rsqrtf((float)(c + 1));
      acc[n] = b2f(g[(size_t)(v + n) * 64 + lane]);  // self term
      pm = pd[n] > pm ? pd[n] : pm;
    }
    for (int j = 0; j < pm; j += 16) {
      u32 cw[4][8];
      bool act[4];
#pragma unroll
      for (int n = 0; n < 4; ++n) {
        act[n] = j < pd[n];
        if (act[n]) {
          int b = rs[n] + j;
          uint4 c0 = *(const uint4*)(csr + b);
          uint4 c1 = *(const uint4*)(csr + b + 8);
          cw[n][0] = c0.x; cw[n][1] = c0.y; cw[n][2] = c0.z; cw[n][3] = c0.w;
          cw[n][4] = c1.x; cw[n][5] = c1.y; cw[n][6] = c1.z; cw[n][7] = c1.w;
        }
      }
      float hh[4][16];
#pragma unroll
      for (int n = 0; n < 4; ++n) {
        if (act[n]) {
#pragma unroll
          for (int i = 0; i < 8; ++i) {
            hh[n][2 * i] = b2f(g[(size_t)(cw[n][i] & 0xFFFFu) * 64 + lane]);
            hh[n][2 * i + 1] = b2f(g[(size_t)(cw[n][i] >> 16) * 64 + lane]);
          }
        }
      }
#pragma unroll
      for (int n = 0; n < 4; ++n) {
        if (act[n]) {
          float s0 = (hh[n][0] + hh[n][1]) + (hh[n][2] + hh[n][3]);
          float s1 = (hh[n][4] + hh[n][5]) + (hh[n][6] + hh[n][7]);
          float s2 = (hh[n][8] + hh[n][9]) + (hh[n][10] + hh[n][11]);
          float s3 = (hh[n][12] + hh[n][13]) + (hh[n][14] + hh[n][15]);
          acc[n] += (s0 + s1) + (s2 + s3);
        }
      }
    }
    float bv = b2f(bias[lane]);
    float wfv = w2f[lane];
    float val[4];
#pragma unroll
    for (int n = 0; n < 4; ++n) {
      val[n] = fmaxf(dvl[n] * acc[n] + bv, 0.0f) * wfv;
      for (int o = 32; o > 0; o >>= 1) val[n] += __shfl_xor(val[n], o);
    }
#pragma unroll
    for (int n = 0; n < 4; ++n)
      if (lane == n) tvec[v + n] = dvl[n] * val[n];
  }
}

// K3: scalar agg + sigmoid: four nodes/wave, 16 lanes each.
__global__ __launch_bounds__(256) void k_aggz(const float* __restrict__ tvec,
                                              const int* __restrict__ rowstart,
                                              const int* __restrict__ cnt,
                                              const u16* __restrict__ csr,
                                              const float* __restrict__ cbias,
                                              void* __restrict__ out,
                                              const int* __restrict__ flags) {
  int tid = threadIdx.x;
  int wave = tid >> 6, lane = tid & 63;
  int sub = lane >> 4, slot = lane & 15;
  int v = blockIdx.x * 16 + wave * 4 + sub;  // NN%16==0 -> v < NN
  for (int rep = 0; rep < REPS; ++rep) {
    int rs = rowstart[v];
    int cv = cnt[v];
    int pdeg = (cv + 15) & ~15;
    float acc = 0.f;
    for (int j = slot; j < pdeg; j += 16) acc += tvec[csr[rs + j]];
    for (int o = 8; o > 0; o >>= 1) acc += __shfl_xor(acc, o);
    if (slot == 0) {
      float dv = rsqrtf((float)(cv + 1));
      float z = dv * (acc + tvec[v]) + cbias[0];
      float sg = 1.0f / (1.0f + __expf(-z));
      if (flags[0]) ((u16*)out)[v] = f2b(sg);
      else ((float*)out)[v] = sg;
    }
  }
}

extern "C" void kernel_launch(void* const* d_in, const int* in_sizes, int n_in,
                              void* d_out, int out_size, void* d_ws, size_t ws_size,
                              hipStream_t stream) {
  const void* x = d_in[0];
  const int* ei = (const int*)d_in[1];
  const void* W1 = d_in[2];
  const u16* b1 = (const u16*)d_in[3];
  const void* W2 = d_in[4];
  const u16* b2 = (const u16*)d_in[5];
  const void* Wfc = d_in[6];
  const u16* bfc = (const u16*)d_in[7];

  int E = in_sizes[1] / 2;
  const int* src = ei;
  const int* dst = ei + E;

  char* base = (char*)d_ws;
  size_t off = 0;
  auto alloc = [&](size_t bytes) {
    void* p = base + off;
    off = (off + bytes + 255) & ~(size_t)255;
    return p;
  };
  int* flags = (int*)alloc(8 * 4);
  float* w2f = (float*)alloc(64 * 4);
  float* cbias = (float*)alloc(4);
  int* cnt = (int*)alloc((size_t)NN * 4);
  int* rowstart = (int*)alloc((size_t)NN * 4);
  u32* bucket = (u32*)alloc((size_t)NBINB * NREG * CAP2 * 4);  // 12.8 MB
  u8* cntm = (u8*)alloc((size_t)NBINB * NREG);                 // 100 KB
  u16* csr = (u16*)alloc((size_t)NREG * SLAB * 2);
  float* gf = (float*)alloc((size_t)NN * 64 * 4);              // unscaled h1
  u16* g = (u16*)alloc((size_t)(NN + 1) * 64 * 2);  // dinv-scaled h1 + 0 row
  float* tvec = (float*)alloc((size_t)(NN + 1) * 4);  // tscaled + 0 sentinel

  // K0) misc prep (1) || one-pass binning (512) || unscaled MFMA GEMM (782)
  k_prep_bin_gemm<<<1 + NBINB + NGEMB, 256, 0, stream>>>(
      (const u32*)x, in_sizes[0] / 2, W1, in_sizes[2] / 2, W2, in_sizes[4] / 2,
      Wfc, in_sizes[6] / 2, b2, bfc, w2f, cbias, flags, src, dst, E, bucket,
      cntm, x, gf, g, tvec);
  // K1) per-region assemble: cnt/rowstart/csr + dinv-scale gf -> g
  k_assemble<<<NREG, 512, 0, stream>>>(bucket, cntm, rowstart, cnt, csr, gf, g);
  // K2) layer-1 agg + relu + head projection -> tscaled
  k_agg1t<<<NN / 16, 256, 0, stream>>>(g, cnt, rowstart, csr, b1, w2f, tvec);
  // K3) scalar agg + sigmoid -> out
  k_aggz<<<NN / 16, 256, 0, stream>>>(tvec, rowstart, cnt, csr, cbias, d_out,
                                      flags);
}

// Round 6
// 142.649 us; speedup vs baseline: 1.4609x; 1.4609x over previous
//
#include <hip/hip_runtime.h>
#include <hip/hip_bf16.h>

#define NN 50000
#define FIN 128
#define NT (NN / 16)   // 3125 row-tiles of 16
#define NREG 196       // ceil(NN/256) 256-node regions
#define SLAB 8960      // fixed per-region CSR slab (max padded region ~8150)
#define NBINB 512      // binning chunks (1562 edges each)
#define CAP2 32        // per-(chunk,region) cell capacity = one 128B line
#define NGEMB ((NT + 3) / 4)  // 782 GEMM blocks
#define STCAP 5200     // LDS stage capacity (region mean 4082, +17 sigma)

typedef unsigned char u8;
typedef unsigned short u16;
typedef unsigned int u32;
typedef __attribute__((ext_vector_type(8))) short short8;
typedef __attribute__((ext_vector_type(4))) float floatx4;

__device__ __forceinline__ float b2f(u16 v) {
  union { u32 u; float f; } x; x.u = ((u32)v) << 16; return x.f;
}
__device__ __forceinline__ u16 f2b(float f) {
  union { u32 u; float f; } x; x.f = f;
  u32 r = x.u + 0x7FFFu + ((x.u >> 16) & 1u);  // round-nearest-even
  return (u16)(r >> 16);
}
__device__ __forceinline__ float lo16(u32 u) {
  union { u32 x; float f; } c; c.x = u << 16; return c.f;
}
__device__ __forceinline__ float hi16(u32 u) {
  union { u32 x; float f; } c; c.x = u & 0xFFFF0000u; return c.f;
}

// K0: three independent parts, GEMM blocks FIRST (long pole dispatches first):
//  blk 0..NGEMB-1        : self-contained MFMA GEMM  gu = bf16(x @ W1)
//                          (UNSCALED -> no dependence on degrees at all).
//  blk NGEMB..+NBINB-1   : one-pass edge binning into (chunk,region) cells.
//  last blk              : w2f = W2@Wfc, cbias, flags, sentinel rows.
__global__ __launch_bounds__(256) void k_prep_bin_gemm(
    const u32* __restrict__ xw, int nxw, const void* __restrict__ w1, int n1w,
    const void* __restrict__ w2, int n2w, const void* __restrict__ wf, int nfw,
    const u16* __restrict__ b2, const u16* __restrict__ bfc,
    float* __restrict__ w2f, float* __restrict__ cbias, int* __restrict__ flags,
    const int* __restrict__ src, const int* __restrict__ dst, int E,
    u32* __restrict__ bucket, u8* __restrict__ cntm,
    const void* __restrict__ X, u16* __restrict__ g,
    float* __restrict__ dinv, float* __restrict__ tvec) {
  int t = threadIdx.x;
  int blk = blockIdx.x;
  if (blk >= NGEMB && blk < NGEMB + NBINB) {  // ---- one-pass binning ----
    __shared__ int cnt2[NREG];
    for (int i = t; i < NREG; i += 256) cnt2[i] = 0;
    __syncthreads();
    int sl = blk - NGEMB;
    int lo = (int)((long long)sl * E / NBINB);
    int hi = (int)((long long)(sl + 1) * E / NBINB);
    for (int e = lo + t; e < hi; e += 256) {
      int d = dst[e];
      int s = src[e];
      int r = d >> 8;
      int ofs = atomicAdd(&cnt2[r], 1);
      if (ofs < CAP2)
        bucket[((size_t)sl * NREG + r) * CAP2 + ofs] =
            ((u32)(d & 255) << 16) | (u32)s;
    }
    __syncthreads();
    for (int i = t; i < NREG; i += 256) {
      int c = cnt2[i];
      cntm[(size_t)sl * NREG + i] = (u8)(c > CAP2 ? CAP2 : c);
    }
    return;
  }
  if (blk >= NGEMB + NBINB) {  // ---- misc: flags, w2f, cbias, sentinels ----
    __shared__ int sc[3];
    if (t < 3) sc[t] = 0;
    __syncthreads();
    const u32* p2 = (const u32*)w2;
    const u32* pf = (const u32*)wf;
    int n2s = n2w < 1024 ? n2w : 1024;
    int nfs = nfw < 1024 ? nfw : 1024;
    int sn = nxw < 1024 ? nxw : 1024;
    int s2 = 0, sf = 0, sx = 0;
    for (int i = t; i < n2s; i += 256) {
      u32 w = p2[i];
      u32 e = (w >> 7) & 0xFFu;
      s2 += (e >= 100u && e <= 132u) ? 1 : -1;
    }
    for (int i = t; i < nfs; i += 256) {
      u32 w = pf[i];
      u32 e = (w >> 7) & 0xFFu;
      sf += (e >= 100u && e <= 132u) ? 1 : -1;
    }
    for (int i = t; i < sn; i += 256) {
      u32 w = xw[i];
      u32 e = (w >> 7) & 0xFFu;
      sx += (e >= 100u && e <= 132u) ? 1 : -1;
    }
    if (s2) atomicAdd(&sc[0], s2);
    if (sf) atomicAdd(&sc[1], sf);
    if (sx) atomicAdd(&sc[2], sx);
    __syncthreads();
    int f2 = sc[0] > 0, f3 = sc[1] > 0;
    if (t == 0) { flags[0] = sc[2] > 0; flags[2] = f2; flags[3] = f3; }
    if (t < 64) {
      float acc = 0.f;
      for (int j = 0; j < 64; ++j) {
        float w2v = f2 ? b2f(((const u16*)w2)[t * 64 + j])
                       : ((const float*)w2)[t * 64 + j];
        float wfv = f3 ? b2f(((const u16*)wf)[j]) : ((const float*)wf)[j];
        acc += w2v * wfv;
      }
      w2f[t] = acc;
    } else if (t == 64) {
      float acc = b2f(bfc[0]);
      for (int j = 0; j < 64; ++j) {
        float wfv = f3 ? b2f(((const u16*)wf)[j]) : ((const float*)wf)[j];
        acc += b2f(b2[j]) * wfv;
      }
      cbias[0] = acc;
    } else if (t >= 128 && t < 192) {
      g[(size_t)NN * 64 + (t - 128)] = 0;  // sentinel row gu[NN] = 0
    } else if (t == 192) {
      tvec[NN] = 0.f;  // sentinel tscaled[NN] = 0
    } else if (t == 193) {
      dinv[NN] = 0.f;  // sentinel dinv[NN] = 0 (pads contribute exactly 0)
    }
    return;
  }
  // ---- GEMM: gu = bf16(x @ W1), unscaled ----
  __shared__ u16 lwh[FIN * 64];
  __shared__ u16 lwl[FIN * 64];
  __shared__ int scg[2];
  if (t < 2) scg[t] = 0;
  __syncthreads();
  {  // self-detect x / W1 formats (deterministic, same result in every block)
    int sn = nxw < 1024 ? nxw : 1024;
    int sx = 0;
    for (int i = t; i < sn; i += 256) {
      u32 w = xw[i];
      u32 e = (w >> 7) & 0xFFu;
      sx += (e >= 100u && e <= 132u) ? 1 : -1;
    }
    if (sx) atomicAdd(&scg[0], sx);
    int s1n = n1w < 1024 ? n1w : 1024;
    const u32* p1 = (const u32*)w1;
    int s1 = 0;
    for (int i = t; i < s1n; i += 256) {
      u32 w = p1[i];
      u32 e = (w >> 7) & 0xFFu;
      s1 += (e >= 100u && e <= 132u) ? 1 : -1;
    }
    if (s1) atomicAdd(&scg[1], s1);
  }
  __syncthreads();
  bool xb = scg[0] > 0;
  bool w1b = scg[1] > 0;
  for (int i = t; i < FIN * 64; i += 256) {
    int j = i & 7, L = (i >> 3) & 63, f = i >> 9;
    int k = (f >> 2) * 32 + (L >> 4) * 8 + j;
    int n = (f & 3) * 16 + (L & 15);
    int idx = k * 64 + n;
    float v = w1b ? b2f(((const u16*)w1)[idx]) : ((const float*)w1)[idx];
    u16 hb = f2b(v);
    lwh[i] = hb;
    lwl[i] = f2b(v - b2f(hb));
  }
  __syncthreads();
  constexpr int KC = FIN / 32;
  int wave = t >> 6, lane = t & 63;
  int rt = blk * 4 + wave;
  if (rt >= NT) return;
  int m = rt * 16 + (lane & 15);
  int q = (lane >> 4) * 8;
  short8 ah[KC], al[KC];
  if (xb) {
    const u16* xr = (const u16*)X + (size_t)m * FIN + q;
#pragma unroll
    for (int kc = 0; kc < KC; ++kc) ah[kc] = *(const short8*)(xr + kc * 32);
  } else {
    const float* xr = (const float*)X + (size_t)m * FIN + q;
#pragma unroll
    for (int kc = 0; kc < KC; ++kc) {
      float4 v0 = *(const float4*)(xr + kc * 32);
      float4 v1 = *(const float4*)(xr + kc * 32 + 4);
      float v[8] = {v0.x, v0.y, v0.z, v0.w, v1.x, v1.y, v1.z, v1.w};
      short8 h8, l8;
#pragma unroll
      for (int j = 0; j < 8; ++j) {
        u16 hb = f2b(v[j]);
        h8[j] = (short)hb;
        l8[j] = (short)f2b(v[j] - b2f(hb));
      }
      ah[kc] = h8;
      al[kc] = l8;
    }
  }
  int row0 = rt * 16 + (lane >> 4) * 4;
  int c0 = lane & 15;
#pragma unroll
  for (int ct = 0; ct < 4; ++ct) {
    short8 bh[KC], bl[KC];
#pragma unroll
    for (int kc = 0; kc < KC; ++kc) {
      int fo = ((kc * 4 + ct) * 64 + lane) * 8;
      bh[kc] = *(const short8*)(lwh + fo);
      bl[kc] = *(const short8*)(lwl + fo);
    }
    floatx4 acc = (floatx4)(0.f);
#pragma unroll
    for (int kc = 0; kc < KC; ++kc) {
      if (!xb)
        acc = __builtin_amdgcn_mfma_f32_16x16x32_bf16(al[kc], bh[kc], acc, 0, 0, 0);
      acc = __builtin_amdgcn_mfma_f32_16x16x32_bf16(ah[kc], bl[kc], acc, 0, 0, 0);
      acc = __builtin_amdgcn_mfma_f32_16x16x32_bf16(ah[kc], bh[kc], acc, 0, 0, 0);
    }
    size_t o = (size_t)row0 * 64 + ct * 16 + c0;
#pragma unroll
    for (int r = 0; r < 4; ++r) g[o + (size_t)r * 64] = f2b(acc[r]);
  }
}

// K1: one block per region (512 thr). Scan 512 chunk counts -> gather cells
// into LDS stage -> node histogram -> rowstart/cnt/dinv -> csr scatter +
// sentinel pad. (No g work: GEMM writes final unscaled gu in K0.)
__global__ __launch_bounds__(512) void k_assemble(
    const u32* __restrict__ bucket, const u8* __restrict__ cntm,
    int* __restrict__ rowstart, int* __restrict__ cnt,
    float* __restrict__ dinv, u16* __restrict__ csr) {
  __shared__ u32 stage[STCAP];
  __shared__ int h[256];
  __shared__ int off[256];
  __shared__ int wsum[8];
  __shared__ int nws[4];
  __shared__ int tot_s;
  int r = blockIdx.x, t = threadIdx.x;
  int lane = t & 63, w = t >> 6;
  int c = (int)cntm[(size_t)t * NREG + r];
  int xv = c;
  for (int d = 1; d < 64; d <<= 1) {
    int y = __shfl_up(xv, d);
    if (lane >= d) xv += y;
  }
  if (lane == 63) wsum[w] = xv;
  if (t < 256) h[t] = 0;
  __syncthreads();
  int add = 0;
  for (int j = 0; j < w; ++j) add += wsum[j];
  int beg = xv + add - c;
  if (t == 0) {
    int tt = 0;
    for (int j = 0; j < 8; ++j) tt += wsum[j];
    tot_s = tt > STCAP ? STCAP : tt;
  }
  const u32* b = bucket + ((size_t)t * NREG + r) * CAP2;
  for (int i = 0; i < c; ++i) {
    int p = beg + i;
    if (p < STCAP) stage[p] = b[i];
  }
  __syncthreads();
  int tot = tot_s;
  for (int i = t; i < tot; i += 512) atomicAdd(&h[stage[i] >> 16], 1);
  __syncthreads();
  int grs = 0, p16 = 0, hc = 0, sv = 0;
  if (t < 256) {
    hc = h[t];
    p16 = (hc + 15) & ~15;
    sv = p16;
    for (int d = 1; d < 64; d <<= 1) {
      int y = __shfl_up(sv, d);
      if (lane >= d) sv += y;
    }
    if (lane == 63) nws[w] = sv;
  }
  __syncthreads();
  if (t < 256) {
    int a2 = 0;
    for (int j = 0; j < w; ++j) a2 += nws[j];
    sv += a2;
    grs = r * SLAB + sv - p16;
    int v = r * 256 + t;
    if (v < NN) {
      rowstart[v] = grs;
      cnt[v] = hc;
      dinv[v] = rsqrtf((float)(hc + 1));
    }
    off[t] = grs;
  }
  __syncthreads();
  for (int i = t; i < tot; i += 512) {
    u32 pk = stage[i];
    int pos = atomicAdd(&off[pk >> 16], 1);
    csr[pos] = (u16)(pk & 0xFFFFu);
  }
  __syncthreads();
  if (t < 256) {
    int v = r * 256 + t;
    if (v < NN) {
      int end = grs + p16;
      for (int pos = off[t]; pos < end; ++pos) csr[pos] = (u16)NN;
    }
  }
}

// K2: layer-1 agg + relu + head projection. FOUR nodes/wave, TWO COLS/LANE,
// TWO ROWS PER GATHER INSTRUCTION: lanes 0..31 (half 0) fetch srcs j..j+7,
// lanes 32..63 (half 1) fetch srcs j+8..j+15, each lane reading a u32
// (2 bf16 cols) of gu. dinv[src] is applied at gather time (broadcast load
// from the L2-resident dinv table):
//   tvec[v] = dinv_v * ( relu( dinv_v*(sum_s dinv_s*gu[s] + dinv_v*gu[v]) + b1 ) . w2f )
__global__ __launch_bounds__(256) void k_agg1t(const u32* __restrict__ gu,
                                               const float* __restrict__ dinv,
                                               const int* __restrict__ cnt,
                                               const int* __restrict__ rowstart,
                                               const u16* __restrict__ csr,
                                               const u16* __restrict__ bias,
                                               const float* __restrict__ w2f,
                                               float* __restrict__ tvec) {
  int tid = threadIdx.x;
  int wave = tid >> 6, lane = tid & 63;
  int hf = lane >> 5, c2 = lane & 31;  // half, column-pair (cols 2c2, 2c2+1)
  int v = (blockIdx.x * 4 + wave) * 4;  // NN%16==0 -> v+3 < NN
  int rs[4], pd[4];
  float dvl[4], a0[4], a1[4];
  int pm = 0;
#pragma unroll
  for (int n = 0; n < 4; ++n) {
    rs[n] = rowstart[v + n];
    int c = cnt[v + n];
    pd[n] = (c + 15) & ~15;
    dvl[n] = dinv[v + n];
    u32 u = gu[(size_t)(v + n) * 32 + c2];
    // self term counted once (half 0 only)
    a0[n] = hf ? 0.f : dvl[n] * lo16(u);
    a1[n] = hf ? 0.f : dvl[n] * hi16(u);
    pm = pd[n] > pm ? pd[n] : pm;
  }
  for (int j = 0; j < pm; j += 16) {
#pragma unroll
    for (int n = 0; n < 4; ++n) {
      if (j < pd[n]) {
        uint4 cw = *(const uint4*)(csr + rs[n] + j + hf * 8);
        u32 idv[8] = {cw.x & 0xFFFFu, cw.x >> 16, cw.y & 0xFFFFu, cw.y >> 16,
                      cw.z & 0xFFFFu, cw.z >> 16, cw.w & 0xFFFFu, cw.w >> 16};
#pragma unroll
        for (int i = 0; i < 8; ++i) {
          u32 u = gu[(size_t)idv[i] * 32 + c2];
          float dvs = dinv[idv[i]];
          a0[n] = fmaf(dvs, lo16(u), a0[n]);
          a1[n] = fmaf(dvs, hi16(u), a1[n]);
        }
      }
    }
  }
  float bv0 = b2f(bias[2 * c2]);
  float bv1 = b2f(bias[2 * c2 + 1]);
  float wf0 = w2f[2 * c2];
  float wf1 = w2f[2 * c2 + 1];
#pragma unroll
  for (int n = 0; n < 4; ++n) {
    float s0 = a0[n] + __shfl_xor(a0[n], 32);  // combine src-halves
    float s1 = a1[n] + __shfl_xor(a1[n], 32);
    float val = fmaxf(dvl[n] * s0 + bv0, 0.0f) * wf0 +
                fmaxf(dvl[n] * s1 + bv1, 0.0f) * wf1;
    for (int o = 16; o > 0; o >>= 1) val += __shfl_xor(val, o);
    if (lane == n) tvec[v + n] = dvl[n] * val;
  }
}

// K3: scalar agg + sigmoid: four nodes/wave, 16 lanes each.
// z[v] = dv*(sum tscaled[s] + tscaled[v]) + cbias; sentinel pads add 0.
__global__ __launch_bounds__(256) void k_aggz(const float* __restrict__ tvec,
                                              const float* __restrict__ dinv,
                                              const int* __restrict__ rowstart,
                                              const int* __restrict__ cnt,
                                              const u16* __restrict__ csr,
                                              const float* __restrict__ cbias,
                                              void* __restrict__ out,
                                              const int* __restrict__ flags) {
  int tid = threadIdx.x;
  int wave = tid >> 6, lane = tid & 63;
  int sub = lane >> 4, slot = lane & 15;
  int v = blockIdx.x * 16 + wave * 4 + sub;  // NN%16==0 -> v < NN
  int rs = rowstart[v];
  int pdeg = (cnt[v] + 15) & ~15;
  float acc = 0.f;
  for (int j = slot; j < pdeg; j += 16) acc += tvec[csr[rs + j]];
  for (int o = 8; o > 0; o >>= 1) acc += __shfl_xor(acc, o);
  if (slot == 0) {
    float z = dinv[v] * (acc + tvec[v]) + cbias[0];
    float sg = 1.0f / (1.0f + __expf(-z));
    if (flags[0]) ((u16*)out)[v] = f2b(sg);
    else ((float*)out)[v] = sg;
  }
}

extern "C" void kernel_launch(void* const* d_in, const int* in_sizes, int n_in,
                              void* d_out, int out_size, void* d_ws, size_t ws_size,
                              hipStream_t stream) {
  const void* x = d_in[0];
  const int* ei = (const int*)d_in[1];
  const void* W1 = d_in[2];
  const u16* b1 = (const u16*)d_in[3];
  const void* W2 = d_in[4];
  const u16* b2 = (const u16*)d_in[5];
  const void* Wfc = d_in[6];
  const u16* bfc = (const u16*)d_in[7];

  int E = in_sizes[1] / 2;
  const int* src = ei;
  const int* dst = ei + E;

  char* base = (char*)d_ws;
  size_t off = 0;
  auto alloc = [&](size_t bytes) {
    void* p = base + off;
    off = (off + bytes + 255) & ~(size_t)255;
    return p;
  };
  int* flags = (int*)alloc(8 * 4);
  float* w2f = (float*)alloc(64 * 4);
  float* cbias = (float*)alloc(4);
  int* cnt = (int*)alloc((size_t)NN * 4);
  int* rowstart = (int*)alloc((size_t)NN * 4);
  float* dinv = (float*)alloc((size_t)(NN + 1) * 4);       // + 0 sentinel
  u32* bucket = (u32*)alloc((size_t)NBINB * NREG * CAP2 * 4);  // 12.8 MB
  u8* cntm = (u8*)alloc((size_t)NBINB * NREG);                 // 100 KB
  u16* csr = (u16*)alloc((size_t)NREG * SLAB * 2);
  u16* g = (u16*)alloc((size_t)(NN + 1) * 64 * 2);  // UNSCALED bf16 h1 + 0 row
  float* tvec = (float*)alloc((size_t)(NN + 1) * 4);  // tscaled + 0 sentinel

  // K0) MFMA GEMM gu=bf16(x@W1) (782, first) || binning (512) || misc (1)
  k_prep_bin_gemm<<<NGEMB + NBINB + 1, 256, 0, stream>>>(
      (const u32*)x, in_sizes[0] / 2, W1, in_sizes[2] / 2, W2, in_sizes[4] / 2,
      Wfc, in_sizes[6] / 2, b2, bfc, w2f, cbias, flags, src, dst, E, bucket,
      cntm, x, g, dinv, tvec);
  // K1) per-region assemble: cnt/rowstart/dinv/csr
  k_assemble<<<NREG, 512, 0, stream>>>(bucket, cntm, rowstart, cnt, dinv, csr);
  // K2) layer-1 agg + relu + head projection -> tscaled
  k_agg1t<<<NN / 16, 256, 0, stream>>>((const u32*)g, dinv, cnt, rowstart, csr,
                                       b1, w2f, tvec);
  // K3) scalar agg + sigmoid -> out
  k_aggz<<<NN / 16, 256, 0, stream>>>(tvec, dinv, rowstart, cnt, csr, cbias,
                                      d_out, flags);
}